// Round 8
// baseline (291.226 us; speedup 1.0000x reference)
//
#include <hip/hip_runtime.h>
#include <math.h>

#define DIM 256
#define GBM 128
#define GBN 128
#define GBK 64
#define SCHUNK 1024

typedef short bf16x8 __attribute__((ext_vector_type(8)));
typedef float f32x4 __attribute__((ext_vector_type(4)));

__device__ __forceinline__ ushort f2bf(float f) {
  uint u = __float_as_uint(f);
  u += 0x7fffu + ((u >> 16) & 1u);
  return (ushort)(u >> 16);
}
__device__ __forceinline__ float bf2f(uint bits) {
  return __uint_as_float(bits << 16);
}

// async 16B-per-lane global->LDS DMA (dest = wave-uniform base + lane*16)
__device__ __forceinline__ void async_copy16(const ushort* g, ushort* l) {
  __builtin_amdgcn_global_load_lds(
      (const __attribute__((address_space(1))) unsigned int*)g,
      (__attribute__((address_space(3))) unsigned int*)l, 16, 0, 0);
}

// ---------------------------------------------------------------------------
// prep: fused convert_x (fp32->bf16) + weight concat/cast + dst histogram
// ---------------------------------------------------------------------------
__global__ __launch_bounds__(256) void prep_kernel(
    const float4* __restrict__ x4, ushort* __restrict__ xb, int n4,
    const float* __restrict__ Wl, const float* __restrict__ Wr,
    const float* __restrict__ W2l, const float* __restrict__ W2r,
    ushort* __restrict__ Wb, ushort* __restrict__ W2b,
    const int* __restrict__ dst, int* __restrict__ deg, int E) {
  const int t0 = blockIdx.x * blockDim.x + threadIdx.x;
  const int stride = gridDim.x * blockDim.x;
  for (int i = t0; i < n4; i += stride) {
    const float4 v = x4[i];
    ushort4 o;
    o.x = f2bf(v.x); o.y = f2bf(v.y); o.z = f2bf(v.z); o.w = f2bf(v.w);
    *(ushort4*)&xb[i * 4] = o;
  }
  if (t0 < 131072) {
    const int n = t0 >> 9, k = t0 & 511;
    const float v = (k < 256) ? Wl[n * 256 + k] : Wr[n * 256 + (k - 256)];
    Wb[t0] = f2bf(v);
  } else if (t0 < 135168) {
    const int w2 = t0 - 131072;
    const int row = w2 >> 8, k = w2 & 255;
    float v = 0.f;
    if (row < 2)      v = W2l[row * 256 + k];
    else if (row < 4) v = W2r[(row - 2) * 256 + k];
    W2b[w2] = f2bf(v);
  }
  for (int e = t0; e < E; e += stride) atomicAdd(&deg[dst[e]], 1);
}

// ---------------------------------------------------------------------------
// Scan phase A: per-1024-chunk totals
// ---------------------------------------------------------------------------
__global__ __launch_bounds__(256) void scan_partial(
    const int* __restrict__ deg, int* __restrict__ bsum, int M) {
  const int base = blockIdx.x * SCHUNK + threadIdx.x * 4;
  int s = 0;
  if (base + 3 < M) {
    const int4 v = *(const int4*)(deg + base);
    s = v.x + v.y + v.z + v.w;
  } else {
    for (int j = 0; j < 4; ++j) if (base + j < M) s += deg[base + j];
  }
  #pragma unroll
  for (int off = 32; off; off >>= 1) s += __shfl_xor(s, off);
  __shared__ int ws[4];
  if ((threadIdx.x & 63) == 0) ws[threadIdx.x >> 6] = s;
  __syncthreads();
  if (threadIdx.x == 0) bsum[blockIdx.x] = ws[0] + ws[1] + ws[2] + ws[3];
}

// ---------------------------------------------------------------------------
// Scan phase B: exclusive scan of block sums (one block)
// ---------------------------------------------------------------------------
__global__ __launch_bounds__(1024) void scan_sums(
    int* __restrict__ bsum, int nb) {
  __shared__ int sh[1024];
  const int t = threadIdx.x;
  const int orig = (t < nb) ? bsum[t] : 0;
  sh[t] = orig;
  __syncthreads();
  for (int off = 1; off < 1024; off <<= 1) {
    const int v = sh[t];
    const int u = (t >= off) ? sh[t - off] : 0;
    __syncthreads();
    sh[t] = v + u;
    __syncthreads();
  }
  if (t < nb) bsum[t] = sh[t] - orig;
}

// ---------------------------------------------------------------------------
// Scan phase C: intra-block scan + offset -> rowptr, fill, invc
// ---------------------------------------------------------------------------
__global__ __launch_bounds__(256) void scan_finalize(
    const int* __restrict__ deg, const int* __restrict__ bsum,
    int* __restrict__ rowptr, int* __restrict__ fill,
    float* __restrict__ invc, int M) {
  const int t = threadIdx.x;
  const int lane = t & 63;
  const int wid = t >> 6;
  const int base = blockIdx.x * SCHUNK + t * 4;
  int d[4];
  #pragma unroll
  for (int j = 0; j < 4; ++j) d[j] = (base + j < M) ? deg[base + j] : 0;
  const int tsum = d[0] + d[1] + d[2] + d[3];
  int v = tsum;
  #pragma unroll
  for (int off = 1; off < 64; off <<= 1) {
    const int u = __shfl_up(v, off);
    if (lane >= off) v += u;
  }
  __shared__ int wtot[4];
  if (lane == 63) wtot[wid] = v;
  __syncthreads();
  int wbase = 0;
  for (int w = 0; w < wid; ++w) wbase += wtot[w];
  int run = bsum[blockIdx.x] + wbase + v - tsum;
  #pragma unroll
  for (int j = 0; j < 4; ++j) {
    const int idx = base + j;
    if (idx < M) {
      rowptr[idx] = run;
      fill[idx]   = run;
      invc[idx]   = 1.0f / fmaxf((float)d[j], 1.0f);
      run += d[j];
      if (idx == M - 1) rowptr[M] = run;
    }
  }
}

// ---------------------------------------------------------------------------
// scatter src ids into CSR order
// ---------------------------------------------------------------------------
__global__ __launch_bounds__(256) void scatter_edges(
    const int* __restrict__ src, const int* __restrict__ dst,
    int* __restrict__ fill, int* __restrict__ esrc, int E) {
  int e = blockIdx.x * blockDim.x + threadIdx.x;
  if (e < E) {
    const int pos = atomicAdd(&fill[dst[e]], 1);
    esrc[pos] = src[e];
  }
}

// ---------------------------------------------------------------------------
// Gather-reduce v4: one wave/node, half-wave edge split, software-pipelined:
// next 4 rows (8 edges) prefetched into named regs while current 4 accumulate.
// ---------------------------------------------------------------------------
__global__ __launch_bounds__(256) void gather1(
    const ushort* __restrict__ xb, const int* __restrict__ esrc,
    const int* __restrict__ rowptr, const float* __restrict__ invc,
    ushort* __restrict__ aggb, int M) {
  const int lane = threadIdx.x & 63;
  const int wave = threadIdx.x >> 6;
  const int half = lane >> 5;
  const int fl   = lane & 31;
  const int i = blockIdx.x * 4 + wave;
  if (i >= M) return;
  const int k0 = rowptr[i];
  const int k1 = rowptr[i + 1];
  float s0 = 0.f, s1 = 0.f, s2 = 0.f, s3 = 0.f;
  float s4 = 0.f, s5 = 0.f, s6 = 0.f, s7 = 0.f;

#define ROW(e) (*(const uint4*)(xb + (size_t)(e) * DIM + fl * 8))
#define ACC(v)                                                  \
  do {                                                          \
    s0 += bf2f((v).x & 0xffffu); s1 += bf2f((v).x >> 16);       \
    s2 += bf2f((v).y & 0xffffu); s3 += bf2f((v).y >> 16);       \
    s4 += bf2f((v).z & 0xffffu); s5 += bf2f((v).z >> 16);       \
    s6 += bf2f((v).w & 0xffffu); s7 += bf2f((v).w >> 16);       \
  } while (0)

  int k = k0;
  if (k1 - k0 >= 16) {
    // prologue: first batch of 8 edges (4 rows per half-wave)
    uint4 a0 = ROW(esrc[k + 0 + half]);
    uint4 a1 = ROW(esrc[k + 2 + half]);
    uint4 a2 = ROW(esrc[k + 4 + half]);
    uint4 a3 = ROW(esrc[k + 6 + half]);
    k += 8;
    for (; k + 7 < k1; k += 8) {
      // issue next batch, then accumulate current under the load latency
      const uint4 b0 = ROW(esrc[k + 0 + half]);
      const uint4 b1 = ROW(esrc[k + 2 + half]);
      const uint4 b2 = ROW(esrc[k + 4 + half]);
      const uint4 b3 = ROW(esrc[k + 6 + half]);
      ACC(a0); ACC(a1); ACC(a2); ACC(a3);
      a0 = b0; a1 = b1; a2 = b2; a3 = b3;
    }
    ACC(a0); ACC(a1); ACC(a2); ACC(a3);
  }
  for (; k + 3 < k1; k += 4) {
    const uint4 v0 = ROW(esrc[k + 0 + half]);
    const uint4 v1 = ROW(esrc[k + 2 + half]);
    ACC(v0); ACC(v1);
  }
  for (; k + 1 < k1; k += 2) {
    const uint4 v = ROW(esrc[k + half]);
    ACC(v);
  }
  if (k < k1 && half == 0) {
    const uint4 v = ROW(esrc[k]);
    ACC(v);
  }
#undef ACC
#undef ROW

  s0 += __shfl_xor(s0, 32); s1 += __shfl_xor(s1, 32);
  s2 += __shfl_xor(s2, 32); s3 += __shfl_xor(s3, 32);
  s4 += __shfl_xor(s4, 32); s5 += __shfl_xor(s5, 32);
  s6 += __shfl_xor(s6, 32); s7 += __shfl_xor(s7, 32);

  if (half == 0) {
    const float inv = invc[i];
    uint4 o;
    o.x = (uint)f2bf(s0 * inv) | ((uint)f2bf(s1 * inv) << 16);
    o.y = (uint)f2bf(s2 * inv) | ((uint)f2bf(s3 * inv) << 16);
    o.z = (uint)f2bf(s4 * inv) | ((uint)f2bf(s5 * inv) << 16);
    o.w = (uint)f2bf(s6 * inv) | ((uint)f2bf(s7 * inv) << 16);
    *(uint4*)(aggb + (size_t)i * DIM + fl * 8) = o;
  }
}

// ---------------------------------------------------------------------------
// MFMA GEMM + fused layer-2 projection.
//   C = relu([agg | x] @ [Wl | Wr]^T + b1)   (staged in LDS, never written out)
//   Y4v[row][c] += C[row, colblock] @ W2cat[c, colblock]   (atomicAdd, c=0..3)
// m97 structure: global_load_lds staging, single-buffer linear LDS, 2 barriers.
// OOB staging rows read garbage from adjacent ws buffers (safe: never stored).
// ---------------------------------------------------------------------------
__global__ __launch_bounds__(256) void gemm1_mfma(
    const ushort* __restrict__ Ab, const ushort* __restrict__ Xb,
    const ushort* __restrict__ Wb, const float* __restrict__ b1,
    const ushort* __restrict__ W2b, float* __restrict__ Y4v, int M) {
  __shared__ __align__(16) ushort lds[2 * GBM * GBK];  // 32 KB; reused for C
  ushort* As = lds;
  ushort* Bs = lds + GBM * GBK;

  const int tid  = threadIdx.x;
  const int lane = tid & 63;
  const int wave = tid >> 6;
  const int wm = wave >> 1, wn = wave & 1;
  const int row0 = blockIdx.x * GBM;
  const int col0 = blockIdx.y * GBN;

  const int lsub = lane >> 3;  // row within 8-row staging group
  const int lk   = lane & 7;   // 16B k-chunk

  const int frow = lane & 15;
  const int fk   = (lane >> 4) * 8;

  f32x4 acc[4][4] = {};

  for (int t = 0; t < 8; ++t) {
    const int kt = t * GBK;
    const ushort* srcA = (t < 4) ? Ab : Xb;
    const int kofs = kt & 255;
    #pragma unroll
    for (int i = 0; i < 4; ++i) {
      const int rbase = i * 32 + wave * 8;
      const int r = rbase + lsub;
      async_copy16(srcA + (size_t)(row0 + r) * DIM + kofs + lk * 8,
                   &As[rbase * GBK]);
      async_copy16(Wb + (size_t)(col0 + r) * 512 + kt + lk * 8,
                   &Bs[rbase * GBK]);
    }
    __syncthreads();  // vmcnt(0) drain: tile t in LDS

    #pragma unroll
    for (int s = 0; s < 2; ++s) {
      bf16x8 a[4], b[4];
      #pragma unroll
      for (int i = 0; i < 4; ++i)
        a[i] = *(const bf16x8*)&As[(wm * 64 + i * 16 + frow) * GBK + s * 32 + fk];
      #pragma unroll
      for (int j = 0; j < 4; ++j)
        b[j] = *(const bf16x8*)&Bs[(wn * 64 + j * 16 + frow) * GBK + s * 32 + fk];
      #pragma unroll
      for (int i = 0; i < 4; ++i)
        #pragma unroll
        for (int j = 0; j < 4; ++j)
          acc[i][j] = __builtin_amdgcn_mfma_f32_16x16x32_bf16(a[i], b[j], acc[i][j], 0, 0, 0);
    }
    __syncthreads();
  }

  // stage C = relu(acc + bias) as bf16 into LDS, XOR-swizzled cols
  #pragma unroll
  for (int i = 0; i < 4; ++i) {
    #pragma unroll
    for (int j = 0; j < 4; ++j) {
      const int col = wn * 64 + j * 16 + frow;
      const float bias = b1[col0 + col];
      #pragma unroll
      for (int r = 0; r < 4; ++r) {
        const int row = wm * 64 + i * 16 + (lane >> 4) * 4 + r;
        lds[row * 128 + (col ^ ((row & 7) << 3))] =
            f2bf(fmaxf(acc[i][j][r] + bias, 0.f));
      }
    }
  }
  __syncthreads();

  // fused proj: per wave 2 row-groups; Y4 partial = C(16x128) @ W2cat^T(128x16)
  bf16x8 wfrag[4];
  #pragma unroll
  for (int s2 = 0; s2 < 4; ++s2)
    wfrag[s2] = *(const bf16x8*)(W2b + frow * DIM + col0 + s2 * 32 + fk);

  #pragma unroll
  for (int g = 0; g < 2; ++g) {
    const int grp = wave * 2 + g;
    f32x4 y = {};
    #pragma unroll
    for (int s2 = 0; s2 < 4; ++s2) {
      const int row = grp * 16 + frow;
      const bf16x8 a =
          *(const bf16x8*)&lds[row * 128 + ((s2 * 32 + fk) ^ ((row & 7) << 3))];
      y = __builtin_amdgcn_mfma_f32_16x16x32_bf16(a, wfrag[s2], y, 0, 0, 0);
    }
    const int c = lane & 15;
    if (c < 4) {
      #pragma unroll
      for (int r = 0; r < 4; ++r) {
        const int grow = row0 + grp * 16 + (lane >> 4) * 4 + r;
        if (grow < M) unsafeAtomicAdd(&Y4v[(size_t)grow * 4 + c], y[r]);
      }
    }
  }
}

// ---------------------------------------------------------------------------
// Layer-2 aggregation + bias + log_softmax
// ---------------------------------------------------------------------------
__global__ __launch_bounds__(256) void layer2_finalize(
    const float2* __restrict__ Y2, const int* __restrict__ esrc,
    const int* __restrict__ rowptr, const float* __restrict__ invc,
    const float* __restrict__ b2, float* __restrict__ out, int M) {
  int i = blockIdx.x * blockDim.x + threadIdx.x;
  if (i < M) {
    const int k0 = rowptr[i];
    const int k1 = rowptr[i + 1];
    float a0 = 0.f, a1 = 0.f;
    int k = k0;
    for (; k + 3 < k1; k += 4) {
      const int e0 = esrc[k], e1 = esrc[k + 1], e2 = esrc[k + 2], e3 = esrc[k + 3];
      const float2 y0 = Y2[2 * (size_t)e0];
      const float2 y1 = Y2[2 * (size_t)e1];
      const float2 y2 = Y2[2 * (size_t)e2];
      const float2 y3 = Y2[2 * (size_t)e3];
      a0 += y0.x + y1.x + y2.x + y3.x;
      a1 += y0.y + y1.y + y2.y + y3.y;
    }
    for (; k < k1; ++k) {
      const float2 y = Y2[2 * (size_t)esrc[k]];
      a0 += y.x; a1 += y.y;
    }
    const float inv = invc[i];
    const float2 yr = Y2[2 * (size_t)i + 1];
    const float o0 = a0 * inv + yr.x + b2[0];
    const float o1 = a1 * inv + yr.y + b2[1];
    const float m = fmaxf(o0, o1);
    const float lse = m + logf(expf(o0 - m) + expf(o1 - m));
    out[2 * i + 0] = o0 - lse;
    out[2 * i + 1] = o1 - lse;
  }
}

extern "C" void kernel_launch(void* const* d_in, const int* in_sizes, int n_in,
                              void* d_out, int out_size, void* d_ws, size_t ws_size,
                              hipStream_t stream) {
  const float* x   = (const float*)d_in[0];
  const int*   ei  = (const int*)d_in[1];
  const float* W1l = (const float*)d_in[2];
  const float* b1  = (const float*)d_in[3];
  const float* W1r = (const float*)d_in[4];
  const float* W2l = (const float*)d_in[5];
  const float* b2  = (const float*)d_in[6];
  const float* W2r = (const float*)d_in[7];

  const int E = in_sizes[1] / 2;
  const int M = in_sizes[0] / DIM;  // 50000
  const int* src = ei;
  const int* dst = ei + E;

  char* ws = (char*)d_ws;
  size_t off = 0;
  // zero region: Y4v (layer-2 partial accumulators) + deg
  float* Y4v  = (float*)(ws + off);  off += (size_t)M * 4 * 4;
  int* deg    = (int*)(ws + off);    off += (size_t)M * 4;
  const size_t zbytes = off;
  ushort* xb   = (ushort*)(ws + off); off += (size_t)M * DIM * 2;
  ushort* aggb = (ushort*)(ws + off); off += (size_t)M * DIM * 2;
  ushort* Wb   = (ushort*)(ws + off); off += (size_t)256 * 512 * 2;
  ushort* W2b  = (ushort*)(ws + off); off += (size_t)16 * 256 * 2;
  float* invc  = (float*)(ws + off);  off += (size_t)M * 4;
  int* fill    = (int*)(ws + off);    off += (size_t)M * 4;
  int* rowptr  = (int*)(ws + off);    off += (size_t)(M + 1) * 4;
  int* bsum    = (int*)(ws + off);    off += 1024 * 4;
  int* esrc    = (int*)(ws + off);    off += (size_t)E * 4;

  hipMemsetAsync(d_ws, 0, zbytes, stream);

  const int EB = (E + 255) / 256;
  const int NB = (M + SCHUNK - 1) / SCHUNK;

  prep_kernel<<<2048, 256, 0, stream>>>((const float4*)x, xb, M * DIM / 4,
                                        W1l, W1r, W2l, W2r, Wb, W2b, dst, deg, E);
  scan_partial<<<NB, 256, 0, stream>>>(deg, bsum, M);
  scan_sums<<<1, 1024, 0, stream>>>(bsum, NB);
  scan_finalize<<<NB, 256, 0, stream>>>(deg, bsum, rowptr, fill, invc, M);
  scatter_edges<<<EB, 256, 0, stream>>>(src, dst, fill, esrc, E);
  gather1<<<(M + 3) / 4, 256, 0, stream>>>(xb, esrc, rowptr, invc, aggb, M);

  dim3 g1((M + GBM - 1) / GBM, DIM / GBN);
  gemm1_mfma<<<g1, 256, 0, stream>>>(aggb, xb, Wb, b1, W2b, Y4v, M);

  layer2_finalize<<<(M + 255) / 256, 256, 0, stream>>>(
      (const float2*)Y4v, esrc, rowptr, invc, b2, (float*)d_out, M);
}

// Round 9
// 271.488 us; speedup vs baseline: 1.0727x; 1.0727x over previous
//
#include <hip/hip_runtime.h>
#include <math.h>

#define DIM 256
#define GBM 128
#define GBN 128
#define GBK 64
#define SCHUNK 1024

typedef short bf16x8 __attribute__((ext_vector_type(8)));
typedef float f32x4 __attribute__((ext_vector_type(4)));
typedef float f32x2 __attribute__((ext_vector_type(2)));

__device__ __forceinline__ ushort f2bf(float f) {
  uint u = __float_as_uint(f);
  u += 0x7fffu + ((u >> 16) & 1u);
  return (ushort)(u >> 16);
}
__device__ __forceinline__ float bf2f(uint bits) {
  return __uint_as_float(bits << 16);
}

// async 16B-per-lane global->LDS DMA (dest = wave-uniform base + lane*16)
__device__ __forceinline__ void async_copy16(const ushort* g, ushort* l) {
  __builtin_amdgcn_global_load_lds(
      (const __attribute__((address_space(1))) unsigned int*)g,
      (__attribute__((address_space(3))) unsigned int*)l, 16, 0, 0);
}

// ---------------------------------------------------------------------------
// prep: convert_x (fp32 -> bf16 AND fp8 e4m3) + weight concat/cast + histogram
// ---------------------------------------------------------------------------
__global__ __launch_bounds__(256) void prep_kernel(
    const float4* __restrict__ x4, ushort* __restrict__ xb,
    uint* __restrict__ xq, int n4,
    const float* __restrict__ Wl, const float* __restrict__ Wr,
    const float* __restrict__ W2l, const float* __restrict__ W2r,
    ushort* __restrict__ Wb, ushort* __restrict__ W2b,
    const int* __restrict__ dst, int* __restrict__ deg, int E) {
  const int t0 = blockIdx.x * blockDim.x + threadIdx.x;
  const int stride = gridDim.x * blockDim.x;
  for (int i = t0; i < n4; i += stride) {
    const float4 v = x4[i];
    ushort4 o;
    o.x = f2bf(v.x); o.y = f2bf(v.y); o.z = f2bf(v.z); o.w = f2bf(v.w);
    *(ushort4*)&xb[i * 4] = o;
    // fp8 e4m3 pack: 4 floats -> 1 dword (HW RNE + saturation)
    int q = __builtin_amdgcn_cvt_pk_fp8_f32(v.x, v.y, 0, false);
    q = __builtin_amdgcn_cvt_pk_fp8_f32(v.z, v.w, q, true);
    xq[i] = (uint)q;
  }
  if (t0 < 131072) {
    const int n = t0 >> 9, k = t0 & 511;
    const float v = (k < 256) ? Wl[n * 256 + k] : Wr[n * 256 + (k - 256)];
    Wb[t0] = f2bf(v);
  } else if (t0 < 135168) {
    const int w2 = t0 - 131072;
    const int row = w2 >> 8, k = w2 & 255;
    float v = 0.f;
    if (row < 2)      v = W2l[row * 256 + k];
    else if (row < 4) v = W2r[(row - 2) * 256 + k];
    W2b[w2] = f2bf(v);
  }
  for (int e = t0; e < E; e += stride) atomicAdd(&deg[dst[e]], 1);
}

// ---------------------------------------------------------------------------
// Scan phase A: per-1024-chunk totals
// ---------------------------------------------------------------------------
__global__ __launch_bounds__(256) void scan_partial(
    const int* __restrict__ deg, int* __restrict__ bsum, int M) {
  const int base = blockIdx.x * SCHUNK + threadIdx.x * 4;
  int s = 0;
  if (base + 3 < M) {
    const int4 v = *(const int4*)(deg + base);
    s = v.x + v.y + v.z + v.w;
  } else {
    for (int j = 0; j < 4; ++j) if (base + j < M) s += deg[base + j];
  }
  #pragma unroll
  for (int off = 32; off; off >>= 1) s += __shfl_xor(s, off);
  __shared__ int ws[4];
  if ((threadIdx.x & 63) == 0) ws[threadIdx.x >> 6] = s;
  __syncthreads();
  if (threadIdx.x == 0) bsum[blockIdx.x] = ws[0] + ws[1] + ws[2] + ws[3];
}

// ---------------------------------------------------------------------------
// Scan phase B+C fused: wave 0 reduces bsum[0..bid) for the block offset,
// then intra-block scan -> rowptr, fill, invc.  (nb <= 64 blocks)
// ---------------------------------------------------------------------------
__global__ __launch_bounds__(256) void scan_finalize(
    const int* __restrict__ deg, const int* __restrict__ bsum, int nb,
    int* __restrict__ rowptr, int* __restrict__ fill,
    float* __restrict__ invc, int M) {
  __shared__ int boff_sh;
  const int t = threadIdx.x;
  const int lane = t & 63;
  const int wid = t >> 6;
  if (t < 64) {
    int v = (t < nb && t < (int)blockIdx.x) ? bsum[t] : 0;
    #pragma unroll
    for (int off = 32; off; off >>= 1) v += __shfl_xor(v, off);
    if (t == 0) boff_sh = v;
  }
  const int base = blockIdx.x * SCHUNK + t * 4;
  int d[4];
  #pragma unroll
  for (int j = 0; j < 4; ++j) d[j] = (base + j < M) ? deg[base + j] : 0;
  const int tsum = d[0] + d[1] + d[2] + d[3];
  int v = tsum;
  #pragma unroll
  for (int off = 1; off < 64; off <<= 1) {
    const int u = __shfl_up(v, off);
    if (lane >= off) v += u;
  }
  __shared__ int wtot[4];
  if (lane == 63) wtot[wid] = v;
  __syncthreads();
  int wbase = 0;
  for (int w = 0; w < wid; ++w) wbase += wtot[w];
  int run = boff_sh + wbase + v - tsum;
  #pragma unroll
  for (int j = 0; j < 4; ++j) {
    const int idx = base + j;
    if (idx < M) {
      rowptr[idx] = run;
      fill[idx]   = run;
      invc[idx]   = 1.0f / fmaxf((float)d[j], 1.0f);
      run += d[j];
      if (idx == M - 1) rowptr[M] = run;
    }
  }
}

// ---------------------------------------------------------------------------
// scatter src ids into CSR order
// ---------------------------------------------------------------------------
__global__ __launch_bounds__(256) void scatter_edges(
    const int* __restrict__ src, const int* __restrict__ dst,
    int* __restrict__ fill, int* __restrict__ esrc, int E) {
  int e = blockIdx.x * blockDim.x + threadIdx.x;
  if (e < E) {
    const int pos = atomicAdd(&fill[dst[e]], 1);
    esrc[pos] = src[e];
  }
}

// ---------------------------------------------------------------------------
// Gather-reduce v5: v3 loop structure (known-good) over fp8 rows.
// One wave/node, half-wave edge split, lane loads uint2 = 8 fp8 feats.
// ---------------------------------------------------------------------------
__global__ __launch_bounds__(256) void gather1(
    const uchar* __restrict__ xq, const int* __restrict__ esrc,
    const int* __restrict__ rowptr, const float* __restrict__ invc,
    ushort* __restrict__ aggb, int M) {
  const int lane = threadIdx.x & 63;
  const int wave = threadIdx.x >> 6;
  const int half = lane >> 5;
  const int fl   = lane & 31;
  const int i = blockIdx.x * 4 + wave;
  if (i >= M) return;
  const int k0 = rowptr[i];
  const int k1 = rowptr[i + 1];
  float s0 = 0.f, s1 = 0.f, s2 = 0.f, s3 = 0.f;
  float s4 = 0.f, s5 = 0.f, s6 = 0.f, s7 = 0.f;

#define ROW(e) (*(const uint2*)(xq + (size_t)(e) * DIM + fl * 8))
#define ACC(v)                                                        \
  do {                                                                \
    f32x2 p;                                                          \
    p = __builtin_amdgcn_cvt_pk_f32_fp8((int)(v).x, false);           \
    s0 += p.x; s1 += p.y;                                             \
    p = __builtin_amdgcn_cvt_pk_f32_fp8((int)(v).x, true);            \
    s2 += p.x; s3 += p.y;                                             \
    p = __builtin_amdgcn_cvt_pk_f32_fp8((int)(v).y, false);           \
    s4 += p.x; s5 += p.y;                                             \
    p = __builtin_amdgcn_cvt_pk_f32_fp8((int)(v).y, true);            \
    s6 += p.x; s7 += p.y;                                             \
  } while (0)

  int k = k0;
  for (; k + 7 < k1; k += 8) {
    const int e0 = esrc[k + 0 + half];
    const int e1 = esrc[k + 2 + half];
    const int e2 = esrc[k + 4 + half];
    const int e3 = esrc[k + 6 + half];
    const uint2 v0 = ROW(e0);
    const uint2 v1 = ROW(e1);
    const uint2 v2 = ROW(e2);
    const uint2 v3 = ROW(e3);
    ACC(v0); ACC(v1); ACC(v2); ACC(v3);
  }
  for (; k + 1 < k1; k += 2) {
    const uint2 v = ROW(esrc[k + half]);
    ACC(v);
  }
  if (k < k1 && half == 0) {
    const uint2 v = ROW(esrc[k]);
    ACC(v);
  }
#undef ACC
#undef ROW

  s0 += __shfl_xor(s0, 32); s1 += __shfl_xor(s1, 32);
  s2 += __shfl_xor(s2, 32); s3 += __shfl_xor(s3, 32);
  s4 += __shfl_xor(s4, 32); s5 += __shfl_xor(s5, 32);
  s6 += __shfl_xor(s6, 32); s7 += __shfl_xor(s7, 32);

  if (half == 0) {
    const float inv = invc[i];
    uint4 o;
    o.x = (uint)f2bf(s0 * inv) | ((uint)f2bf(s1 * inv) << 16);
    o.y = (uint)f2bf(s2 * inv) | ((uint)f2bf(s3 * inv) << 16);
    o.z = (uint)f2bf(s4 * inv) | ((uint)f2bf(s5 * inv) << 16);
    o.w = (uint)f2bf(s6 * inv) | ((uint)f2bf(s7 * inv) << 16);
    *(uint4*)(aggb + (size_t)i * DIM + fl * 8) = o;
  }
}

// ---------------------------------------------------------------------------
// MFMA GEMM + fused layer-2 projection.
//   C = relu([agg | x] @ [Wl | Wr]^T + b1)   (staged in LDS, never written out)
//   Y4v[row][c] += C[row, colblock] @ W2cat[c, colblock]   (atomicAdd, c=0..3)
// ---------------------------------------------------------------------------
__global__ __launch_bounds__(256) void gemm1_mfma(
    const ushort* __restrict__ Ab, const ushort* __restrict__ Xb,
    const ushort* __restrict__ Wb, const float* __restrict__ b1,
    const ushort* __restrict__ W2b, float* __restrict__ Y4v, int M) {
  __shared__ __align__(16) ushort lds[2 * GBM * GBK];  // 32 KB; reused for C
  ushort* As = lds;
  ushort* Bs = lds + GBM * GBK;

  const int tid  = threadIdx.x;
  const int lane = tid & 63;
  const int wave = tid >> 6;
  const int wm = wave >> 1, wn = wave & 1;
  const int row0 = blockIdx.x * GBM;
  const int col0 = blockIdx.y * GBN;

  const int lsub = lane >> 3;
  const int lk   = lane & 7;

  const int frow = lane & 15;
  const int fk   = (lane >> 4) * 8;

  f32x4 acc[4][4] = {};

  for (int t = 0; t < 8; ++t) {
    const int kt = t * GBK;
    const ushort* srcA = (t < 4) ? Ab : Xb;
    const int kofs = kt & 255;
    #pragma unroll
    for (int i = 0; i < 4; ++i) {
      const int rbase = i * 32 + wave * 8;
      const int r = rbase + lsub;
      async_copy16(srcA + (size_t)(row0 + r) * DIM + kofs + lk * 8,
                   &As[rbase * GBK]);
      async_copy16(Wb + (size_t)(col0 + r) * 512 + kt + lk * 8,
                   &Bs[rbase * GBK]);
    }
    __syncthreads();

    #pragma unroll
    for (int s = 0; s < 2; ++s) {
      bf16x8 a[4], b[4];
      #pragma unroll
      for (int i = 0; i < 4; ++i)
        a[i] = *(const bf16x8*)&As[(wm * 64 + i * 16 + frow) * GBK + s * 32 + fk];
      #pragma unroll
      for (int j = 0; j < 4; ++j)
        b[j] = *(const bf16x8*)&Bs[(wn * 64 + j * 16 + frow) * GBK + s * 32 + fk];
      #pragma unroll
      for (int i = 0; i < 4; ++i)
        #pragma unroll
        for (int j = 0; j < 4; ++j)
          acc[i][j] = __builtin_amdgcn_mfma_f32_16x16x32_bf16(a[i], b[j], acc[i][j], 0, 0, 0);
    }
    __syncthreads();
  }

  // stage C = relu(acc + bias) as bf16 into LDS, XOR-swizzled cols
  #pragma unroll
  for (int i = 0; i < 4; ++i) {
    #pragma unroll
    for (int j = 0; j < 4; ++j) {
      const int col = wn * 64 + j * 16 + frow;
      const float bias = b1[col0 + col];
      #pragma unroll
      for (int r = 0; r < 4; ++r) {
        const int row = wm * 64 + i * 16 + (lane >> 4) * 4 + r;
        lds[row * 128 + (col ^ ((row & 7) << 3))] =
            f2bf(fmaxf(acc[i][j][r] + bias, 0.f));
      }
    }
  }
  __syncthreads();

  // fused proj: per wave 2 row-groups; Y4 partial = C(16x128) @ W2cat^T(128x16)
  bf16x8 wfrag[4];
  #pragma unroll
  for (int s2 = 0; s2 < 4; ++s2)
    wfrag[s2] = *(const bf16x8*)(W2b + frow * DIM + col0 + s2 * 32 + fk);

  #pragma unroll
  for (int g = 0; g < 2; ++g) {
    const int grp = wave * 2 + g;
    f32x4 y = {};
    #pragma unroll
    for (int s2 = 0; s2 < 4; ++s2) {
      const int row = grp * 16 + frow;
      const bf16x8 a =
          *(const bf16x8*)&lds[row * 128 + ((s2 * 32 + fk) ^ ((row & 7) << 3))];
      y = __builtin_amdgcn_mfma_f32_16x16x32_bf16(a, wfrag[s2], y, 0, 0, 0);
    }
    const int c = lane & 15;
    if (c < 4) {
      #pragma unroll
      for (int r = 0; r < 4; ++r) {
        const int grow = row0 + grp * 16 + (lane >> 4) * 4 + r;
        if (grow < M) unsafeAtomicAdd(&Y4v[(size_t)grow * 4 + c], y[r]);
      }
    }
  }
}

// ---------------------------------------------------------------------------
// Layer-2 aggregation + bias + log_softmax
// ---------------------------------------------------------------------------
__global__ __launch_bounds__(256) void layer2_finalize(
    const float2* __restrict__ Y2, const int* __restrict__ esrc,
    const int* __restrict__ rowptr, const float* __restrict__ invc,
    const float* __restrict__ b2, float* __restrict__ out, int M) {
  int i = blockIdx.x * blockDim.x + threadIdx.x;
  if (i < M) {
    const int k0 = rowptr[i];
    const int k1 = rowptr[i + 1];
    float a0 = 0.f, a1 = 0.f;
    int k = k0;
    for (; k + 3 < k1; k += 4) {
      const int e0 = esrc[k], e1 = esrc[k + 1], e2 = esrc[k + 2], e3 = esrc[k + 3];
      const float2 y0 = Y2[2 * (size_t)e0];
      const float2 y1 = Y2[2 * (size_t)e1];
      const float2 y2 = Y2[2 * (size_t)e2];
      const float2 y3 = Y2[2 * (size_t)e3];
      a0 += y0.x + y1.x + y2.x + y3.x;
      a1 += y0.y + y1.y + y2.y + y3.y;
    }
    for (; k < k1; ++k) {
      const float2 y = Y2[2 * (size_t)esrc[k]];
      a0 += y.x; a1 += y.y;
    }
    const float inv = invc[i];
    const float2 yr = Y2[2 * (size_t)i + 1];
    const float o0 = a0 * inv + yr.x + b2[0];
    const float o1 = a1 * inv + yr.y + b2[1];
    const float m = fmaxf(o0, o1);
    const float lse = m + logf(expf(o0 - m) + expf(o1 - m));
    out[2 * i + 0] = o0 - lse;
    out[2 * i + 1] = o1 - lse;
  }
}

extern "C" void kernel_launch(void* const* d_in, const int* in_sizes, int n_in,
                              void* d_out, int out_size, void* d_ws, size_t ws_size,
                              hipStream_t stream) {
  const float* x   = (const float*)d_in[0];
  const int*   ei  = (const int*)d_in[1];
  const float* W1l = (const float*)d_in[2];
  const float* b1  = (const float*)d_in[3];
  const float* W1r = (const float*)d_in[4];
  const float* W2l = (const float*)d_in[5];
  const float* b2  = (const float*)d_in[6];
  const float* W2r = (const float*)d_in[7];

  const int E = in_sizes[1] / 2;
  const int M = in_sizes[0] / DIM;  // 50000
  const int* src = ei;
  const int* dst = ei + E;

  char* ws = (char*)d_ws;
  size_t off = 0;
  // zero region: Y4v (layer-2 partial accumulators) + deg
  float* Y4v  = (float*)(ws + off);  off += (size_t)M * 4 * 4;
  int* deg    = (int*)(ws + off);    off += (size_t)M * 4;
  const size_t zbytes = off;
  ushort* xb   = (ushort*)(ws + off); off += (size_t)M * DIM * 2;
  uchar* xq    = (uchar*)(ws + off);  off += (size_t)M * DIM;
  ushort* aggb = (ushort*)(ws + off); off += (size_t)M * DIM * 2;
  ushort* Wb   = (ushort*)(ws + off); off += (size_t)256 * 512 * 2;
  ushort* W2b  = (ushort*)(ws + off); off += (size_t)16 * 256 * 2;
  float* invc  = (float*)(ws + off);  off += (size_t)M * 4;
  int* fill    = (int*)(ws + off);    off += (size_t)M * 4;
  int* rowptr  = (int*)(ws + off);    off += (size_t)(M + 1) * 4;
  int* bsum    = (int*)(ws + off);    off += 1024 * 4;
  int* esrc    = (int*)(ws + off);    off += (size_t)E * 4;

  hipMemsetAsync(d_ws, 0, zbytes, stream);

  const int EB = (E + 255) / 256;
  const int NB = (M + SCHUNK - 1) / SCHUNK;  // 49 blocks (<= 64)

  prep_kernel<<<2048, 256, 0, stream>>>((const float4*)x, xb, (uint*)xq,
                                        M * DIM / 4, W1l, W1r, W2l, W2r, Wb, W2b,
                                        dst, deg, E);
  scan_partial<<<NB, 256, 0, stream>>>(deg, bsum, M);
  scan_finalize<<<NB, 256, 0, stream>>>(deg, bsum, NB, rowptr, fill, invc, M);
  scatter_edges<<<EB, 256, 0, stream>>>(src, dst, fill, esrc, E);
  gather1<<<(M + 3) / 4, 256, 0, stream>>>(xq, esrc, rowptr, invc, aggb, M);

  dim3 g1((M + GBM - 1) / GBM, DIM / GBN);
  gemm1_mfma<<<g1, 256, 0, stream>>>(aggb, xb, Wb, b1, W2b, Y4v, M);

  layer2_finalize<<<(M + 255) / 256, 256, 0, stream>>>(
      (const float2*)Y4v, esrc, rowptr, invc, b2, (float*)d_out, M);
}